// Round 2
// baseline (349.675 us; speedup 1.0000x reference)
//
#include <hip/hip_runtime.h>
#include <hip/hip_cooperative_groups.h>

namespace cg = cooperative_groups;

#define B_ 16
#define N_ 1024
#define C_ 768
#define E_ 8
#define H_ 192

typedef __bf16 bf16x8 __attribute__((ext_vector_type(8)));
typedef __bf16 bf16x4 __attribute__((ext_vector_type(4)));
typedef float  f32x4  __attribute__((ext_vector_type(4)));

// ---------------------------------------------------------------------------
// Kernel 1: prep. (a) pack fc1_w/fc2_w to bf16 in MFMA-B-fragment order:
//   pw1[e][kb=c/32][n=h][c%32], pw2[e][kb=h/32][n=c][h%32]
// (b) transpose gate_w to gwT[d][j][c] (f32); rows 0..7 = clean, 8..15 = noise.
// ---------------------------------------------------------------------------
__global__ __launch_bounds__(256) void prep_kernel(
    const float* __restrict__ w1, const float* __restrict__ w2,
    const float* __restrict__ gw,
    __bf16* __restrict__ pw1, __bf16* __restrict__ pw2,
    float* __restrict__ gwT) {
  int idx = blockIdx.x * 256 + threadIdx.x;            // float4 index
  const int nW4 = (E_ * H_ * C_) / 4;                  // 294912
  if (idx >= nW4) return;
  int flat = idx * 4;
  int e = flat / (H_ * C_);
  int r = flat - e * (H_ * C_);

  // w1: [e][h][c] -> pw1
  {
    float4 a = *(const float4*)(w1 + (size_t)flat);
    int n = r / C_;           // h
    int c = r - n * C_;       // c, %4==0
    size_t o = ((size_t)(e * 24 + (c >> 5)) * 192 + n) * 32 + (c & 31);
    pw1[o + 0] = (__bf16)a.x; pw1[o + 1] = (__bf16)a.y;
    pw1[o + 2] = (__bf16)a.z; pw1[o + 3] = (__bf16)a.w;
  }
  // w2: [e][c][h] -> pw2
  {
    float4 a = *(const float4*)(w2 + (size_t)flat);
    int n = r / H_;           // c index 0..767
    int h = r - n * H_;       // 0..191, %4==0
    size_t o = ((size_t)(e * 6 + (h >> 5)) * 768 + n) * 32 + (h & 31);
    pw2[o + 0] = (__bf16)a.x; pw2[o + 1] = (__bf16)a.y;
    pw2[o + 2] = (__bf16)a.z; pw2[o + 3] = (__bf16)a.w;
  }
  // gwT: [d][c][16] -> [d][j][c]
  if (idx < (4 * 16 * C_) / 4) {
    int f = idx * 4;
    int d = f / (16 * C_);
    int rr = f - d * (16 * C_);
    int j = rr / C_;
    int c = rr - j * C_;      // %4==0
    const float* src = gw + (size_t)d * C_ * 16 + j;
    float4 v;
    v.x = src[(size_t)(c + 0) * 16]; v.y = src[(size_t)(c + 1) * 16];
    v.z = src[(size_t)(c + 2) * 16]; v.w = src[(size_t)(c + 3) * 16];
    *(float4*)(gwT + (size_t)f) = v;
  }
}

// ---------------------------------------------------------------------------
// Kernel 2 (cooperative): gate + top-2 + 2-expert adapter in ONE kernel.
// Grid = 256 blocks x 512 thr, 151 KB LDS -> exactly 1 block/CU, all
// co-resident (validated by hipLaunchCooperativeKernel).
// Phase 1: stage own 64x768 x tile f32->LDS in 4 groups of 16 tokens
//   (f32 scratch region later reused as hs); full-precision gating dots
//   (clean+noise, matches the f32 numerics that pass); per-block partial
//   sums -> psums[bid][e]. grid.sync(). Per-sample reduce + top-2.
// Phase 2: round-1 expert body verbatim (x already staged).
// Eliminates: gate kernel (2nd 50MB x pass), xsum atomics, memset, 2 launches.
// ---------------------------------------------------------------------------
#define XS_OFF   0                       // bf16 xs[64][776]  = 99328
#define XF_OFF   99328                   // f32  xf[16][772]  = 49408 (ph1)
#define HS_OFF   99328                   // bf16 hs[64][200]  = 25600 (ph2)
#define SC_OFF   (99328 + 49408)         // f32 sc2[16][16][2] = 2048
#define RED_OFF  (SC_OFF + 2048)         // f32 red[16][8]     = 512
#define BS_OFF   (RED_OFF + 512)         // f32 bsum[8], smc[8] = 64
#define SMEM_FUSED (BS_OFF + 64)         // 151360 B

__global__ __launch_bounds__(512, 2) void fused_kernel(
    const float* __restrict__ x, const int* __restrict__ task_ids,
    const float* __restrict__ eps, const float* __restrict__ gwT,
    const __bf16* __restrict__ pw1, const __bf16* __restrict__ pw2,
    const float* __restrict__ fc1_b, const float* __restrict__ fc2_b,
    float* __restrict__ psums, float* __restrict__ out) {
  const int bid = blockIdx.x;
  const int sxc = bid >> 3;                    // 0..31 within an XCD
  const int b = (bid & 7) * 2 + (sxc >> 4);    // 2 consecutive samples / XCD
  const int token0 = (sxc & 15) * 64;
  const int tid = threadIdx.x;
  const int wave = tid >> 6;
  const int wm = wave >> 2;                    // token half (0/1)
  const int wn = wave & 3;                     // N slice (0..3)
  const int lane = tid & 63;
  const int ln = lane & 15;
  const int q8 = (lane >> 4) * 8;
  const int q4 = (lane >> 4) * 4;
  const int arow = wm * 32;
  const int task = task_ids[b];

  extern __shared__ char smem[];
  __bf16 (*xs)[776] = reinterpret_cast<__bf16(*)[776]>(smem + XS_OFF);
  float  (*xf)[772] = reinterpret_cast<float(*)[772]>(smem + XF_OFF);
  __bf16 (*hs)[200] = reinterpret_cast<__bf16(*)[200]>(smem + HS_OFF);
  float (*sc2)[16][2] = reinterpret_cast<float(*)[16][2]>(smem + SC_OFF);
  float (*red)[8] = reinterpret_cast<float(*)[8]>(smem + RED_OFF);
  float* bsum = reinterpret_cast<float*>(smem + BS_OFF);
  float* smc  = bsum + 8;

  if (tid < 8) bsum[tid] = 0.0f;

  // ---- Phase 1: 4 groups of 16 tokens -------------------------------------
  for (int g = 0; g < 4; ++g) {
    // stage 16x768 f32, coalesced (6 float4 / thread)
    const float* xb = x + ((size_t)b * N_ + token0 + g * 16) * C_;
    for (int it = 0; it < 6; ++it) {
      int chunk = it * 512 + tid;              // 0..3071
      int row = chunk / 192;
      int col4 = (chunk - row * 192) * 4;
      float4 v = *(const float4*)(xb + (size_t)row * C_ + col4);
      *(float4*)&xf[row][col4] = v;
    }
    __syncthreads();

    // gating dots: thread = (t, j, half); f32 exact
    {
      int t = tid >> 5, j = (tid >> 1) & 15, hf = tid & 1;
      const float* wr = gwT + ((size_t)task * 16 + j) * C_ + hf * 384;
      const float* xr_ = &xf[t][hf * 384];
      float acc = 0.0f;
#pragma unroll 4
      for (int c = 0; c < 384; c += 4) {
        float4 xv = *(const float4*)(xr_ + c);
        float4 wv = *(const float4*)(wr + c);
        acc += xv.x * wv.x + xv.y * wv.y + xv.z * wv.z + xv.w * wv.w;
      }
      sc2[t][j][hf] = acc;
    }
    // bf16 conversion into xs (persistent tile for phase 2)
    for (int it = 0; it < 6; ++it) {
      int chunk = it * 512 + tid;
      int row = chunk / 192;
      int col4 = (chunk - row * 192) * 4;
      float4 v = *(const float4*)&xf[row][col4];
      bf16x4 o;
      o[0] = (__bf16)v.x; o[1] = (__bf16)v.y; o[2] = (__bf16)v.z; o[3] = (__bf16)v.w;
      *(bf16x4*)&xs[g * 16 + row][col4] = o;
    }
    __syncthreads();

    // per-token logit: clean + eps * (softplus(raw) + 0.01)
    if (tid < 128) {
      int t = tid >> 3, e = tid & 7;
      float clean = sc2[t][e][0] + sc2[t][e][1];
      float raw   = sc2[t][e + 8][0] + sc2[t][e + 8][1];
      float sp = (raw > 20.0f) ? raw : log1pf(expf(raw));
      red[t][e] = clean +
          eps[((size_t)b * N_ + token0 + g * 16 + t) * E_ + e] * (sp + 0.01f);
    }
    __syncthreads();
    if (tid < 8) {
      float s = bsum[tid];
#pragma unroll
      for (int t = 0; t < 16; ++t) s += red[t][tid];
      bsum[tid] = s;
    }
    // next g's staging only writes xf; dots (which read sc2/red) are after
    // the next iteration's first barrier -> ordered.
  }
  __syncthreads();
  if (tid < 8) psums[bid * 8 + tid] = bsum[tid];
  __threadfence();

  cg::this_grid().sync();

  // per-sample reduce over the sample's 16 tile-blocks
  if (tid < 8) {
    float s = 0.0f;
#pragma unroll
    for (int tile = 0; tile < 16; ++tile) {
      int srcbid = (((b & 1) * 16 + tile) << 3) | (b >> 1);
      s += psums[srcbid * 8 + tid];
    }
    smc[tid] = s;
  }
  __syncthreads();

  // top-2 (tie rule matches lax.top_k: strict >, stable)
  int e_idx[2]; float gate_v[2];
  {
    float best = -INFINITY, best2 = -INFINITY;
    int i1 = 0, i2 = 0;
#pragma unroll
    for (int e = 0; e < E_; ++e) {
      float v = smc[e];
      if (v > best) { best2 = best; i2 = i1; best = v; i1 = e; }
      else if (v > best2) { best2 = v; i2 = e; }
    }
    float d = best - best2;
    float st = d / (d + 1e-6f);
    float et = expf(st);
    e_idx[0] = i1; gate_v[0] = et / (et + 1.0f);
    e_idx[1] = i2; gate_v[1] = 1.0f / (et + 1.0f);
  }

  // ---- Phase 2: expert compute (identical to round-1 body) ----------------
  f32x4 c2[2][12] = {};   // persistent y accumulator (gate folded into h)

  for (int kx = 0; kx < 2; ++kx) {
    const int e = e_idx[kx];
    const float g = gate_v[kx];

    // GEMM1: h = x @ W1^T. M=64 (wm half x 2 frags), N-slice 48 (wn), K=768.
    const __bf16* w1l = pw1 + (size_t)e * (24 * 192 * 32)
                            + (size_t)(wn * 48 + ln) * 32 + q8;
    bf16x8 bq[3][3], aq[3][2];
#pragma unroll
    for (int k0 = 0; k0 < 2; ++k0) {
      const __bf16* nx = w1l + (size_t)k0 * 6144;
#pragma unroll
      for (int jj = 0; jj < 3; ++jj) bq[k0][jj] = *(const bf16x8*)(nx + jj * 512);
      aq[k0][0] = *(const bf16x8*)&xs[arow + ln][k0 * 32 + q8];
      aq[k0][1] = *(const bf16x8*)&xs[arow + 16 + ln][k0 * 32 + q8];
    }
    f32x4 c1[2][3] = {};
#pragma unroll
    for (int kb = 0; kb < 24; ++kb) {
      const int p = kb % 3;
      if (kb < 22) {
        const int kn = kb + 2, pn = kn % 3;
        const __bf16* nx = w1l + (size_t)kn * 6144;
#pragma unroll
        for (int jj = 0; jj < 3; ++jj) bq[pn][jj] = *(const bf16x8*)(nx + jj * 512);
        aq[pn][0] = *(const bf16x8*)&xs[arow + ln][kn * 32 + q8];
        aq[pn][1] = *(const bf16x8*)&xs[arow + 16 + ln][kn * 32 + q8];
      }
#pragma unroll
      for (int jj = 0; jj < 3; ++jj) {
        c1[0][jj] = __builtin_amdgcn_mfma_f32_16x16x32_bf16(aq[p][0], bq[p][jj], c1[0][jj], 0, 0, 0);
        c1[1][jj] = __builtin_amdgcn_mfma_f32_16x16x32_bf16(aq[p][1], bq[p][jj], c1[1][jj], 0, 0, 0);
      }
    }
    // bias + exact gelu + gate scale -> hs (bf16)
#pragma unroll
    for (int jj = 0; jj < 3; ++jj) {
      int col = wn * 48 + jj * 16 + ln;
      float b1 = fc1_b[e * H_ + col];
#pragma unroll
      for (int m = 0; m < 2; ++m) {
#pragma unroll
        for (int r = 0; r < 4; ++r) {
          int row = arow + m * 16 + q4 + r;
          float v = c1[m][jj][r] + b1;
          float gl = 0.5f * v * (1.0f + erff(v * 0.70710678118f));
          hs[row][col] = (__bf16)(g * gl);
        }
      }
    }
    __syncthreads();

    // GEMM2: y += h @ W2^T. M=64 (wm half), N-slice 192 (wn), K=192.
    const __bf16* w2l = pw2 + (size_t)e * (6 * 768 * 32)
                            + (size_t)(wn * 192 + ln) * 32 + q8;
    bf16x8 bh[3][6], av[2][2];
#pragma unroll
    for (int s0 = 0; s0 < 2; ++s0) {
#pragma unroll
      for (int jj = 0; jj < 6; ++jj)
        bh[s0][jj] = *(const bf16x8*)(w2l + (s0 * 6 + jj) * 512);
    }
    av[0][0] = *(const bf16x8*)&hs[arow + ln][q8];
    av[0][1] = *(const bf16x8*)&hs[arow + 16 + ln][q8];
#pragma unroll
    for (int st = 0; st < 12; ++st) {
      const int kb = st >> 1;
      const int half = st & 1;
      const int p = st % 3;
      if (st < 10) {
        const int s2 = st + 2;
        const int kb2 = s2 >> 1, half2 = s2 & 1, p2 = s2 % 3;
        const __bf16* src = w2l + (size_t)kb2 * 24576;
#pragma unroll
        for (int jj = 0; jj < 6; ++jj)
          bh[p2][jj] = *(const bf16x8*)(src + (half2 * 6 + jj) * 512);
        if (half2 == 0) {
          av[kb2 & 1][0] = *(const bf16x8*)&hs[arow + ln][kb2 * 32 + q8];
          av[kb2 & 1][1] = *(const bf16x8*)&hs[arow + 16 + ln][kb2 * 32 + q8];
        }
      }
#pragma unroll
      for (int jj = 0; jj < 6; ++jj) {
        const int cj = half * 6 + jj;
        c2[0][cj] = __builtin_amdgcn_mfma_f32_16x16x32_bf16(av[kb & 1][0], bh[p][jj], c2[0][cj], 0, 0, 0);
        c2[1][cj] = __builtin_amdgcn_mfma_f32_16x16x32_bf16(av[kb & 1][1], bh[p][jj], c2[1][cj], 0, 0, 0);
      }
    }
    __syncthreads();   // protect hs before next expert overwrites
  }

  // epilogue: out = x + y (+ gate-weighted fc2_b)
  const float* xr = x + ((size_t)b * N_ + token0) * C_;
  float* outr = out + ((size_t)b * N_ + token0) * C_;
#pragma unroll
  for (int jj = 0; jj < 12; ++jj) {
    int col = wn * 192 + jj * 16 + ln;
    float b2t = gate_v[0] * fc2_b[e_idx[0] * C_ + col] +
                gate_v[1] * fc2_b[e_idx[1] * C_ + col];
#pragma unroll
    for (int m = 0; m < 2; ++m) {
#pragma unroll
      for (int r = 0; r < 4; ++r) {
        int row = arow + m * 16 + q4 + r;
        size_t off = (size_t)row * C_ + col;
        outr[off] = xr[off] + c2[m][jj][r] + b2t;
      }
    }
  }
}

// ---------------------------------------------------------------------------
extern "C" void kernel_launch(void* const* d_in, const int* in_sizes, int n_in,
                              void* d_out, int out_size, void* d_ws, size_t ws_size,
                              hipStream_t stream) {
  const float* x      = (const float*)d_in[0];
  const int*   task   = (const int*)d_in[1];
  const float* eps    = (const float*)d_in[2];
  const float* gate_w = (const float*)d_in[3];
  const float* fc1_w  = (const float*)d_in[4];
  const float* fc1_b  = (const float*)d_in[5];
  const float* fc2_w  = (const float*)d_in[6];
  const float* fc2_b  = (const float*)d_in[7];
  float* out = (float*)d_out;

  // workspace: pw1 | pw2 | gwT | psums  (~4.92 MB)
  const size_t nW = (size_t)E_ * H_ * C_;              // 1179648
  __bf16* pw1 = (__bf16*)d_ws;
  __bf16* pw2 = pw1 + nW;
  float* gwT   = (float*)((char*)d_ws + 2 * nW * sizeof(__bf16));
  float* psums = gwT + 4 * 16 * C_;                    // 256*8 floats

  prep_kernel<<<(nW / 4 + 255) / 256, 256, 0, stream>>>(fc1_w, fc2_w, gate_w,
                                                        pw1, pw2, gwT);

  hipFuncSetAttribute(reinterpret_cast<const void*>(fused_kernel),
                      hipFuncAttributeMaxDynamicSharedMemorySize, SMEM_FUSED);
  void* args[] = {(void*)&x, (void*)&task, (void*)&eps, (void*)&gwT,
                  (void*)&pw1, (void*)&pw2, (void*)&fc1_b, (void*)&fc2_b,
                  (void*)&psums, (void*)&out};
  hipLaunchCooperativeKernel(reinterpret_cast<void*>(fused_kernel),
                             dim3(B_ * 16), dim3(512), args, SMEM_FUSED,
                             stream);
}

// Round 3
// 206.013 us; speedup vs baseline: 1.6973x; 1.6973x over previous
//
#include <hip/hip_runtime.h>

#define B_ 16
#define N_ 1024
#define C_ 768
#define E_ 8
#define H_ 192

typedef __bf16 bf16x8 __attribute__((ext_vector_type(8)));
typedef float  f32x4  __attribute__((ext_vector_type(4)));

// ---------------------------------------------------------------------------
// Kernel 1: prep. (a) pack fc1_w/fc2_w to bf16 in MFMA-B-fragment order:
//   pw1[e][kb=c/32][n=h][c%32], pw2[e][kb=h/32][n=c][h%32]
// (b) transpose gate_w to gwT[d][j][c] (f32); rows 0..7 clean, 8..15 noise.
// ---------------------------------------------------------------------------
__global__ __launch_bounds__(256) void prep_kernel(
    const float* __restrict__ w1, const float* __restrict__ w2,
    const float* __restrict__ gw,
    __bf16* __restrict__ pw1, __bf16* __restrict__ pw2,
    float* __restrict__ gwT) {
  int idx = blockIdx.x * 256 + threadIdx.x;            // float4 index
  const int nW4 = (E_ * H_ * C_) / 4;                  // 294912
  if (idx >= nW4) return;
  int flat = idx * 4;
  int e = flat / (H_ * C_);
  int r = flat - e * (H_ * C_);

  // w1: [e][h][c] -> pw1
  {
    float4 a = *(const float4*)(w1 + (size_t)flat);
    int n = r / C_;           // h
    int c = r - n * C_;       // c, %4==0
    size_t o = ((size_t)(e * 24 + (c >> 5)) * 192 + n) * 32 + (c & 31);
    pw1[o + 0] = (__bf16)a.x; pw1[o + 1] = (__bf16)a.y;
    pw1[o + 2] = (__bf16)a.z; pw1[o + 3] = (__bf16)a.w;
  }
  // w2: [e][c][h] -> pw2
  {
    float4 a = *(const float4*)(w2 + (size_t)flat);
    int n = r / H_;           // c index 0..767
    int h = r - n * H_;       // 0..191, %4==0
    size_t o = ((size_t)(e * 6 + (h >> 5)) * 768 + n) * 32 + (h & 31);
    pw2[o + 0] = (__bf16)a.x; pw2[o + 1] = (__bf16)a.y;
    pw2[o + 2] = (__bf16)a.z; pw2[o + 3] = (__bf16)a.w;
  }
  // gwT: [d][c][16] -> [d][j][c]
  if (idx < (4 * 16 * C_) / 4) {
    int f = idx * 4;
    int d = f / (16 * C_);
    int rr = f - d * (16 * C_);
    int j = rr / C_;
    int c = rr - j * C_;      // %4==0
    const float* src = gw + (size_t)d * C_ * 16 + j;
    float4 v;
    v.x = src[(size_t)(c + 0) * 16]; v.y = src[(size_t)(c + 1) * 16];
    v.z = src[(size_t)(c + 2) * 16]; v.w = src[(size_t)(c + 3) * 16];
    *(float4*)(gwT + (size_t)f) = v;
  }
}

// ---------------------------------------------------------------------------
// Kernel 2: gating. Grid = B*64 blocks, 16 tokens each, 256 thr (R0 mapping:
// 16 lanes share one gwT row -> broadcast loads, 4 addrs/wave). Per-block
// partial expert sums go to psums[bid][8] (no atomics, no memset).
// ---------------------------------------------------------------------------
__global__ __launch_bounds__(256, 3) void gate_kernel(
    const float* __restrict__ x, const int* __restrict__ task_ids,
    const float* __restrict__ eps, const float* __restrict__ gwT,
    float* __restrict__ psums) {
  const int b = blockIdx.x >> 6;
  const int token0 = (blockIdx.x & 63) * 16;
  const int tid = threadIdx.x;

  __shared__ __align__(16) float xt[16][772];   // pad 4: 2-way (free) reads
  __shared__ float sc[16][16];
  __shared__ float red[16][8];

  // stage 16x768 f32, coalesced: 3072 float4 / 256 thr = 12 each
  const float* xbase = x + ((size_t)b * N_ + token0) * C_;
  for (int it = 0; it < 12; ++it) {
    int chunk = it * 256 + tid;                 // 0..3071
    int row = chunk / 192;
    int col4 = chunk - row * 192;
    float4 v = *(const float4*)(xbase + (size_t)row * C_ + col4 * 4);
    *(float4*)&xt[row][col4 * 4] = v;
  }
  __syncthreads();

  const int t = tid & 15;
  const int j = tid >> 4;                       // 16 lanes share one j
  const int task = task_ids[b];
  const float* wrow = gwT + ((size_t)task * 16 + j) * C_;
  float acc = 0.0f;
#pragma unroll 4
  for (int c = 0; c < C_; c += 4) {
    float4 xv = *(const float4*)&xt[t][c];
    float4 wv = *(const float4*)(wrow + c);
    acc += xv.x * wv.x + xv.y * wv.y + xv.z * wv.z + xv.w * wv.w;
  }
  sc[t][j] = acc;
  __syncthreads();
  if (j < 8) {
    float clean = sc[t][j];
    float raw = sc[t][j + 8];
    float sp = (raw > 20.0f) ? raw : log1pf(expf(raw));
    red[t][j] = clean +
        eps[((size_t)b * N_ + token0 + t) * E_ + j] * (sp + 0.01f);
  }
  __syncthreads();
  if (tid < 8) {
    float s = 0.0f;
#pragma unroll
    for (int tt = 0; tt < 16; ++tt) s += red[tt][tid];
    psums[(size_t)blockIdx.x * 8 + tid] = s;
  }
}

// ---------------------------------------------------------------------------
// Kernel 3: top-2 + 2-expert adapter. Grid = 256 blocks x 512 thr (8 waves =
// 2 token-halves x 4 N-slices), 64 tokens/block, XCD-pinned (bid%8 = XCD,
// 2 samples/XCD -> expert set L2-resident). Changes vs R1:
//  - psums reduce (wave e, shuffle) + top-2 in-kernel, no atomics/memset
//  - GEMM1 prefetch depth 4 ([4][3] rotation, load-after-consume)
//  - GEMM2 B depth 3 ([3][6]), A 3-slot rotation
//  - expert-0 B-tiles issued BEFORE x staging (cold-miss overlap)
// MFMA 16x16x32 bf16; C/D: col=lane&15, row=(lane>>4)*4+reg.
// ---------------------------------------------------------------------------
#define SMEM_EXPERT (64 * 776 * 2 + 64 * 200 * 2 + 32)   // 124960 B

__global__ __launch_bounds__(512, 2) void expert_kernel(
    const float* __restrict__ x, const __bf16* __restrict__ pw1,
    const __bf16* __restrict__ pw2, const float* __restrict__ fc1_b,
    const float* __restrict__ fc2_b, const float* __restrict__ psums,
    float* __restrict__ out) {
  const int bid = blockIdx.x;
  const int sxc = bid >> 3;                    // 0..31 within an XCD
  const int b = (bid & 7) * 2 + (sxc >> 4);    // 2 consecutive samples / XCD
  const int token0 = (sxc & 15) * 64;
  const int tid = threadIdx.x;
  const int wave = tid >> 6;
  const int wm = wave >> 2;                    // token half (0/1)
  const int wn = wave & 3;                     // N slice (0..3)
  const int lane = tid & 63;
  const int ln = lane & 15;
  const int q8 = (lane >> 4) * 8;
  const int q4 = (lane >> 4) * 4;
  const int arow = wm * 32;

  extern __shared__ char smem[];
  __bf16 (*xs)[776] = reinterpret_cast<__bf16(*)[776]>(smem);          // 99328
  __bf16 (*hs)[200] = reinterpret_cast<__bf16(*)[200]>(smem + 99328);  // 25600
  float* smc = reinterpret_cast<float*>(smem + 99328 + 25600);         // 32

  // ---- per-sample gate sums: wave e reduces 64 tile-partials ---------------
  {
    float v = psums[(((size_t)b << 6) | lane) * 8 + wave];
#pragma unroll
    for (int off = 32; off; off >>= 1) v += __shfl_down(v, off);
    if (lane == 0) smc[wave] = v;
  }
  __syncthreads();

  // top-2 (tie rule matches lax.top_k: strict >, stable)
  int e_idx[2]; float gate_v[2];
  {
    float best = -INFINITY, best2 = -INFINITY;
    int i1 = 0, i2 = 0;
#pragma unroll
    for (int e = 0; e < E_; ++e) {
      float v = smc[e];
      if (v > best) { best2 = best; i2 = i1; best = v; i1 = e; }
      else if (v > best2) { best2 = v; i2 = e; }
    }
    float d = best - best2;
    float st = d / (d + 1e-6f);
    float et = expf(st);
    e_idx[0] = i1; gate_v[0] = et / (et + 1.0f);
    e_idx[1] = i2; gate_v[1] = 1.0f / (et + 1.0f);
  }

  // ---- early B-tile preload for expert 0 (overlaps x staging) -------------
  bf16x8 bq[4][3];
  {
    const __bf16* w1l = pw1 + (size_t)e_idx[0] * (24 * 192 * 32)
                            + (size_t)(wn * 48 + ln) * 32 + q8;
#pragma unroll
    for (int k0 = 0; k0 < 4; ++k0)
#pragma unroll
      for (int jj = 0; jj < 3; ++jj)
        bq[k0][jj] = *(const bf16x8*)(w1l + (size_t)k0 * 6144 + jj * 512);
  }

  // ---- stage x tile 64x768 f32->bf16 (coalesced, b128 LDS writes) ---------
  const float* xbase = x + ((size_t)b * N_ + token0) * C_;
  for (int it = 0; it < 12; ++it) {
    int chunk = it * 512 + tid;                // 0..6143
    int row = chunk / 96;
    int col8 = chunk - row * 96;
    const float* p = xbase + (size_t)row * C_ + col8 * 8;
    float4 v0 = *(const float4*)p;
    float4 v1 = *(const float4*)(p + 4);
    bf16x8 tv;
    tv[0] = (__bf16)v0.x; tv[1] = (__bf16)v0.y; tv[2] = (__bf16)v0.z; tv[3] = (__bf16)v0.w;
    tv[4] = (__bf16)v1.x; tv[5] = (__bf16)v1.y; tv[6] = (__bf16)v1.z; tv[7] = (__bf16)v1.w;
    *(bf16x8*)&xs[row][col8 * 8] = tv;
  }
  __syncthreads();

  f32x4 c2[2][12] = {};   // persistent y accumulator (gate folded into h)

  for (int kx = 0; kx < 2; ++kx) {
    const int e = e_idx[kx];
    const float g = gate_v[kx];

    // ---- GEMM1: h = x @ W1^T. M=64 (wm), N-slice 48 (wn), K=768 (24 kb).
    // Depth-4: slots 0..3 preloaded; at kb, consume slot kb&3 then refill
    // it with kb+4 (load-after-consume keeps the rotation at 4 slots).
    const __bf16* w1l = pw1 + (size_t)e * (24 * 192 * 32)
                            + (size_t)(wn * 48 + ln) * 32 + q8;
    if (kx == 1) {
#pragma unroll
      for (int k0 = 0; k0 < 4; ++k0)
#pragma unroll
        for (int jj = 0; jj < 3; ++jj)
          bq[k0][jj] = *(const bf16x8*)(w1l + (size_t)k0 * 6144 + jj * 512);
    }
    bf16x8 aq[4][2];
#pragma unroll
    for (int k0 = 0; k0 < 4; ++k0) {
      aq[k0][0] = *(const bf16x8*)&xs[arow + ln][k0 * 32 + q8];
      aq[k0][1] = *(const bf16x8*)&xs[arow + 16 + ln][k0 * 32 + q8];
    }
    f32x4 c1[2][3] = {};
#pragma unroll
    for (int kb = 0; kb < 24; ++kb) {
      const int p = kb & 3;
#pragma unroll
      for (int jj = 0; jj < 3; ++jj) {
        c1[0][jj] = __builtin_amdgcn_mfma_f32_16x16x32_bf16(aq[p][0], bq[p][jj], c1[0][jj], 0, 0, 0);
        c1[1][jj] = __builtin_amdgcn_mfma_f32_16x16x32_bf16(aq[p][1], bq[p][jj], c1[1][jj], 0, 0, 0);
      }
      if (kb < 20) {
        const int kn = kb + 4;
        const __bf16* nx = w1l + (size_t)kn * 6144;
#pragma unroll
        for (int jj = 0; jj < 3; ++jj) bq[p][jj] = *(const bf16x8*)(nx + jj * 512);
        aq[p][0] = *(const bf16x8*)&xs[arow + ln][kn * 32 + q8];
        aq[p][1] = *(const bf16x8*)&xs[arow + 16 + ln][kn * 32 + q8];
      }
    }
    // bias + exact gelu + gate scale -> hs (bf16)
#pragma unroll
    for (int jj = 0; jj < 3; ++jj) {
      int col = wn * 48 + jj * 16 + ln;
      float b1 = fc1_b[e * H_ + col];
#pragma unroll
      for (int m = 0; m < 2; ++m) {
#pragma unroll
        for (int r = 0; r < 4; ++r) {
          int row = arow + m * 16 + q4 + r;
          float v = c1[m][jj][r] + b1;
          float gl = 0.5f * v * (1.0f + erff(v * 0.70710678118f));
          hs[row][col] = (__bf16)(g * gl);
        }
      }
    }
    __syncthreads();

    // ---- GEMM2: y += h @ W2^T. M=64 (wm), N-slice 192 (wn), K=192.
    // 12 steps (6 kb x 2 half-tiles); B depth-3 ([3][6] rotation,
    // load-after-consume), A 3-slot rotation (av[kb%3]).
    const __bf16* w2l = pw2 + (size_t)e * (6 * 768 * 32)
                            + (size_t)(wn * 192 + ln) * 32 + q8;
    bf16x8 bh[3][6], av[3][2];
#pragma unroll
    for (int s0 = 0; s0 < 3; ++s0) {
      const __bf16* src = w2l + (size_t)(s0 >> 1) * 24576;
#pragma unroll
      for (int jj = 0; jj < 6; ++jj)
        bh[s0][jj] = *(const bf16x8*)(src + ((s0 & 1) * 6 + jj) * 512);
    }
    av[0][0] = *(const bf16x8*)&hs[arow + ln][q8];
    av[0][1] = *(const bf16x8*)&hs[arow + 16 + ln][q8];
    av[1][0] = *(const bf16x8*)&hs[arow + ln][32 + q8];
    av[1][1] = *(const bf16x8*)&hs[arow + 16 + ln][32 + q8];
#pragma unroll
    for (int st = 0; st < 12; ++st) {
      const int kb = st >> 1;
      const int half = st & 1;
      const int p = st % 3;
      const int as = kb % 3;
#pragma unroll
      for (int jj = 0; jj < 6; ++jj) {
        const int cj = half * 6 + jj;
        c2[0][cj] = __builtin_amdgcn_mfma_f32_16x16x32_bf16(av[as][0], bh[p][jj], c2[0][cj], 0, 0, 0);
        c2[1][cj] = __builtin_amdgcn_mfma_f32_16x16x32_bf16(av[as][1], bh[p][jj], c2[1][cj], 0, 0, 0);
      }
      if (st < 9) {
        const int s2 = st + 3;
        const int kb2 = s2 >> 1, half2 = s2 & 1;
        const __bf16* src = w2l + (size_t)kb2 * 24576;
#pragma unroll
        for (int jj = 0; jj < 6; ++jj)
          bh[p][jj] = *(const bf16x8*)(src + (half2 * 6 + jj) * 512);
        if (half2 == 0) {   // st odd: next-next kb's A frags, slot kb2%3 free
          av[kb2 % 3][0] = *(const bf16x8*)&hs[arow + ln][kb2 * 32 + q8];
          av[kb2 % 3][1] = *(const bf16x8*)&hs[arow + 16 + ln][kb2 * 32 + q8];
        }
      }
    }
    __syncthreads();   // protect hs before next expert overwrites
  }

  // epilogue: out = x + y (+ gate-weighted fc2_b)
  const float* xr = x + ((size_t)b * N_ + token0) * C_;
  float* outr = out + ((size_t)b * N_ + token0) * C_;
#pragma unroll
  for (int jj = 0; jj < 12; ++jj) {
    int col = wn * 192 + jj * 16 + ln;
    float b2t = gate_v[0] * fc2_b[e_idx[0] * C_ + col] +
                gate_v[1] * fc2_b[e_idx[1] * C_ + col];
#pragma unroll
    for (int m = 0; m < 2; ++m) {
#pragma unroll
      for (int r = 0; r < 4; ++r) {
        int row = arow + m * 16 + q4 + r;
        size_t off = (size_t)row * C_ + col;
        outr[off] = xr[off] + c2[m][jj][r] + b2t;
      }
    }
  }
}

// ---------------------------------------------------------------------------
extern "C" void kernel_launch(void* const* d_in, const int* in_sizes, int n_in,
                              void* d_out, int out_size, void* d_ws, size_t ws_size,
                              hipStream_t stream) {
  const float* x      = (const float*)d_in[0];
  const int*   task   = (const int*)d_in[1];
  const float* eps    = (const float*)d_in[2];
  const float* gate_w = (const float*)d_in[3];
  const float* fc1_w  = (const float*)d_in[4];
  const float* fc1_b  = (const float*)d_in[5];
  const float* fc2_w  = (const float*)d_in[6];
  const float* fc2_b  = (const float*)d_in[7];
  float* out = (float*)d_out;

  // workspace: pw1 | pw2 | gwT | psums  (~4.95 MB)
  const size_t nW = (size_t)E_ * H_ * C_;              // 1179648
  __bf16* pw1 = (__bf16*)d_ws;
  __bf16* pw2 = pw1 + nW;
  float* gwT   = (float*)((char*)d_ws + 2 * nW * sizeof(__bf16));
  float* psums = gwT + 4 * 16 * C_;                    // 1024*8 floats

  prep_kernel<<<(nW / 4 + 255) / 256, 256, 0, stream>>>(fc1_w, fc2_w, gate_w,
                                                        pw1, pw2, gwT);
  gate_kernel<<<B_ * 64, 256, 0, stream>>>(x, task, eps, gwT, psums);

  hipFuncSetAttribute(reinterpret_cast<const void*>(expert_kernel),
                      hipFuncAttributeMaxDynamicSharedMemorySize, SMEM_EXPERT);
  expert_kernel<<<B_ * 16, 512, SMEM_EXPERT, stream>>>(
      x, pw1, pw2, fc1_b, fc2_b, psums, out);
}